// Round 1
// baseline (662.365 us; speedup 1.0000x reference)
//
#include <hip/hip_runtime.h>
#include <math.h>

#define EPS 1e-5f
constexpr int IMG_H = 1024;
constexpr int IMG_W = 1024;
constexpr int NIMG  = 32;

__device__ __forceinline__ float frelu(float v) { return fmaxf(v, 0.f); }

// ---------------------------------------------------------------------------
// K1: x1 = relu(bn(conv3x3_wa(x)))  and  i1 = reverse cummax over width.
// Block = 256 threads = 4 waves; each wave computes 2 rows of one 8-row strip.
// Lane l owns cols {4l+256q+k : q=0..3, k=0..3}; conv neighbors via shfl.
// ---------------------------------------------------------------------------
__global__ __launch_bounds__(256) void k_conv_rowscan(
    const float* __restrict__ x,
    const float* __restrict__ wa, const float* __restrict__ ba,
    const float* __restrict__ ga, const float* __restrict__ bta,
    const float* __restrict__ ma, const float* __restrict__ va,
    float* __restrict__ x1, float* __restrict__ i1)
{
    const int bid   = blockIdx.x;
    const int img   = bid >> 7;          // 128 strips per image
    const int strip = bid & 127;
    const int r0    = strip * 8;
    const int lane  = threadIdx.x & 63;
    const int wv    = threadIdx.x >> 6;
    const int rb    = r0 + wv * 2;       // first output row of this wave

    const float scale = ga[0] * rsqrtf(va[0] + EPS);
    float w_s[9];
#pragma unroll
    for (int k = 0; k < 9; ++k) w_s[k] = wa[k] * scale;
    const float bias = (ba[0] - ma[0]) * scale + bta[0];

    const float* xim  = x  + (size_t)img * IMG_H * IMG_W;
    float*       x1im = x1 + (size_t)img * IMG_H * IMG_W;
    float*       i1im = i1 + (size_t)img * IMG_H * IMG_W;

    // load 4 input rows (rb-1 .. rb+2), zero-padded vertically
    float4 X[4][4];
#pragma unroll
    for (int ri = 0; ri < 4; ++ri) {
        const int gr = rb - 1 + ri;
        if (gr >= 0 && gr < IMG_H) {
            const float4* rp = (const float4*)(xim + (size_t)gr * IMG_W);
#pragma unroll
            for (int q = 0; q < 4; ++q) X[ri][q] = rp[lane + 64 * q];
        } else {
#pragma unroll
            for (int q = 0; q < 4; ++q) X[ri][q] = make_float4(0.f, 0.f, 0.f, 0.f);
        }
    }

#pragma unroll
    for (int rr = 0; rr < 2; ++rr) {
        const int row = rb + rr;
        float4 v[4];
#pragma unroll
        for (int q = 0; q < 4; ++q) {
            float acc0 = bias, acc1 = bias, acc2 = bias, acc3 = bias;
#pragma unroll
            for (int dy = 0; dy < 3; ++dy) {
                float4 C = X[rr + dy][q];
                float Lw = __shfl_up(C.w, 1, 64);
                float Bq = 0.f;
                if (q > 0) Bq = __shfl(X[rr + dy][q - 1].w, 63, 64);
                if (lane == 0) Lw = Bq;
                float Rx = __shfl_down(C.x, 1, 64);
                float Aq = 0.f;
                if (q < 3) Aq = __shfl(X[rr + dy][q + 1].x, 0, 64);
                if (lane == 63) Rx = Aq;
                const float w0 = w_s[3 * dy], w1 = w_s[3 * dy + 1], w2 = w_s[3 * dy + 2];
                acc0 += w0 * Lw  + w1 * C.x + w2 * C.y;
                acc1 += w0 * C.x + w1 * C.y + w2 * C.z;
                acc2 += w0 * C.y + w1 * C.z + w2 * C.w;
                acc3 += w0 * C.z + w1 * C.w + w2 * Rx;
            }
            v[q] = make_float4(frelu(acc0), frelu(acc1), frelu(acc2), frelu(acc3));
        }
        // reverse (suffix) max scan over the full row
        float4 s[4]; float T[4]; float e[4];
#pragma unroll
        for (int q = 0; q < 4; ++q) {
            float s3 = v[q].w;
            float s2 = fmaxf(v[q].z, s3);
            float s1 = fmaxf(v[q].y, s2);
            float s0 = fmaxf(v[q].x, s1);
            s[q] = make_float4(s0, s1, s2, s3);
            float m = s0;                       // chunk max
#pragma unroll
            for (int off = 1; off < 64; off <<= 1) {
                float o = __shfl_down(m, off, 64);
                if (lane + off < 64) m = fmaxf(m, o);
            }                                   // m = max over lanes >= lane
            T[q] = __shfl(m, 0, 64);            // wave max of chunk q
            float ex = __shfl_down(m, 1, 64);   // max over lanes > lane
            if (lane == 63) ex = -INFINITY;
            e[q] = ex;
        }
        float R[4];
        R[3] = -INFINITY;
        R[2] = T[3];
        R[1] = fmaxf(T[2], R[2]);
        R[0] = fmaxf(T[1], R[1]);

        float4* ox = (float4*)(x1im + (size_t)row * IMG_W);
        float4* oi = (float4*)(i1im + (size_t)row * IMG_W);
#pragma unroll
        for (int q = 0; q < 4; ++q) {
            const float ee = fmaxf(e[q], R[q]);
            float4 iv = make_float4(fmaxf(s[q].x, ee), fmaxf(s[q].y, ee),
                                    fmaxf(s[q].z, ee), fmaxf(s[q].w, ee));
            ox[lane + 64 * q] = v[q];
            oi[lane + 64 * q] = iv;
        }
    }
}

// ---------------------------------------------------------------------------
// K2: bottom-up column scan. i2 = running max of x1; writes t = i1 + i2
// IN PLACE over x1 (read-before-write per element, columns disjoint).
// ---------------------------------------------------------------------------
#define UN 16
__global__ __launch_bounds__(64) void k_colscan(
    const float* __restrict__ i1, float* __restrict__ x1t)
{
    const int bid = blockIdx.x;          // 32 img * 16 strips of 64 cols
    const int img = bid >> 4;
    const int c   = ((bid & 15) << 6) + threadIdx.x;
    const size_t base = (size_t)img * IMG_H * IMG_W + c;

    float rm = -INFINITY;
    for (int h0 = IMG_H - UN; h0 >= 0; h0 -= UN) {
        float xv[UN], iv[UN], tv[UN];
#pragma unroll
        for (int j = 0; j < UN; ++j) xv[j] = x1t[base + (size_t)(h0 + j) * IMG_W];
#pragma unroll
        for (int j = 0; j < UN; ++j) iv[j] = i1[base + (size_t)(h0 + j) * IMG_W];
#pragma unroll
        for (int j = UN - 1; j >= 0; --j) {
            rm = fmaxf(rm, xv[j]);
            tv[j] = iv[j] + rm;
        }
#pragma unroll
        for (int j = 0; j < UN; ++j) x1t[base + (size_t)(h0 + j) * IMG_W] = tv[j];
    }
}

// ---------------------------------------------------------------------------
// K3: fused tail.  Per 64x64 output tile:
//   stage t (70x70, 3-halo) -> LDS
//   s  = relu(bn(conv_wb(t)) + bn(conv1x1_wc(x)))   (68x68, zero outside img)
//   a1 = relu(bn(conv_wa(s)))                        (66x66, zero outside img)
//   out= conv1x1_we(relu(conv_wd(a1) + bd))          (64x64)
// ---------------------------------------------------------------------------
__global__ __launch_bounds__(256) void k_tail(
    const float* __restrict__ t, const float* __restrict__ x,
    const float* __restrict__ wa, const float* __restrict__ ba,
    const float* __restrict__ ga, const float* __restrict__ bta,
    const float* __restrict__ ma, const float* __restrict__ va,
    const float* __restrict__ wb, const float* __restrict__ bb,
    const float* __restrict__ gb, const float* __restrict__ btb,
    const float* __restrict__ mb, const float* __restrict__ vb,
    const float* __restrict__ wc, const float* __restrict__ bc,
    const float* __restrict__ gcp, const float* __restrict__ btc,
    const float* __restrict__ mc, const float* __restrict__ vc,
    const float* __restrict__ wd, const float* __restrict__ bd,
    const float* __restrict__ we, const float* __restrict__ be,
    float* __restrict__ out)
{
    __shared__ float bufT[70 * 72];
    __shared__ float bufS[68 * 72];

    const int bid = blockIdx.x;
    const int img = bid >> 8;
    const int tr  = (bid >> 4) & 15;
    const int tc  = bid & 15;
    const int r0  = tr * 64, c0 = tc * 64;
    const int tid = threadIdx.x;

    const float sa = ga[0] * rsqrtf(va[0] + EPS);
    float was[9];
#pragma unroll
    for (int k = 0; k < 9; ++k) was[k] = wa[k] * sa;
    const float biasa = (ba[0] - ma[0]) * sa + bta[0];

    const float sb = gb[0] * rsqrtf(vb[0] + EPS);
    float wbs[9];
#pragma unroll
    for (int k = 0; k < 9; ++k) wbs[k] = wb[k] * sb;
    const float biasb = (bb[0] - mb[0]) * sb + btb[0];

    const float sc = gcp[0] * rsqrtf(vc[0] + EPS);
    const float kc = wc[0] * sc;
    const float biasc = (bc[0] - mc[0]) * sc + btc[0];

    float wd9[9];
#pragma unroll
    for (int k = 0; k < 9; ++k) wd9[k] = wd[k];
    const float bd0 = bd[0], we0 = we[0], be0 = be[0];

    const float* tim = t + (size_t)img * IMG_H * IMG_W;
    const float* xim = x + (size_t)img * IMG_H * IMG_W;

    // stage t tile (+3 halo), zero padded
    for (int idx = tid; idx < 70 * 70; idx += 256) {
        const int rr = idx / 70, jj = idx - rr * 70;
        const int gr = r0 - 3 + rr, gc2 = c0 - 3 + jj;
        float v = 0.f;
        if ((unsigned)gr < (unsigned)IMG_H && (unsigned)gc2 < (unsigned)IMG_W)
            v = tim[(size_t)gr * IMG_W + gc2];
        bufT[rr * 72 + jj] = v;
    }
    __syncthreads();

    // stage S: 68x68 region at (r0-2, c0-2); 4x4 mini-tile per loop step
    for (int mt = tid; mt < 17 * 17; mt += 256) {
        const int si0 = (mt / 17) * 4, sj0 = (mt % 17) * 4;
        float win[6][6];
#pragma unroll
        for (int r = 0; r < 6; ++r) {
            const float* p = &bufT[(si0 + r) * 72 + sj0];
            float4 a4 = *(const float4*)p;
            float2 b2 = *(const float2*)(p + 4);
            win[r][0] = a4.x; win[r][1] = a4.y; win[r][2] = a4.z; win[r][3] = a4.w;
            win[r][4] = b2.x; win[r][5] = b2.y;
        }
#pragma unroll
        for (int a = 0; a < 4; ++a) {
            float res[4];
#pragma unroll
            for (int b = 0; b < 4; ++b) {
                float acc = biasb;
#pragma unroll
                for (int dy = 0; dy < 3; ++dy)
#pragma unroll
                    for (int dx = 0; dx < 3; ++dx)
                        acc += wbs[3 * dy + dx] * win[a + dy][b + dx];
                const int gr = r0 - 2 + si0 + a, gcc = c0 - 2 + sj0 + b;
                float sres = 0.f;
                if ((unsigned)gr < (unsigned)IMG_H && (unsigned)gcc < (unsigned)IMG_W) {
                    const float xv = xim[(size_t)gr * IMG_W + gcc];
                    sres = frelu(acc + xv * kc + biasc);
                }
                res[b] = sres;
            }
            *(float4*)&bufS[(si0 + a) * 72 + sj0] =
                make_float4(res[0], res[1], res[2], res[3]);
        }
    }
    __syncthreads();

    // stage A: a1 over 66x66 at (r0-1, c0-1); written into bufT (t is dead)
    for (int mt = tid; mt < 17 * 17; mt += 256) {
        const int ai0 = (mt / 17) * 4, aj0 = (mt % 17) * 4;
        float win[6][6];
#pragma unroll
        for (int r = 0; r < 6; ++r) {
            const int rrow = (ai0 + r < 68) ? (ai0 + r) : 67;  // clamp; only garbage lanes use it
            const float* p = &bufS[rrow * 72 + aj0];
            float4 a4 = *(const float4*)p;
            float2 b2 = *(const float2*)(p + 4);
            win[r][0] = a4.x; win[r][1] = a4.y; win[r][2] = a4.z; win[r][3] = a4.w;
            win[r][4] = b2.x; win[r][5] = b2.y;
        }
#pragma unroll
        for (int a = 0; a < 4; ++a) {
            float res[4];
#pragma unroll
            for (int b = 0; b < 4; ++b) {
                float acc = biasa;
#pragma unroll
                for (int dy = 0; dy < 3; ++dy)
#pragma unroll
                    for (int dx = 0; dx < 3; ++dx)
                        acc += was[3 * dy + dx] * win[a + dy][b + dx];
                const int gr = r0 - 1 + ai0 + a, gcc = c0 - 1 + aj0 + b;
                float r1 = 0.f;
                if ((unsigned)gr < (unsigned)IMG_H && (unsigned)gcc < (unsigned)IMG_W)
                    r1 = frelu(acc);
                res[b] = r1;
            }
            *(float4*)&bufT[(ai0 + a) * 72 + aj0] =
                make_float4(res[0], res[1], res[2], res[3]);
        }
    }
    __syncthreads();

    // final: 64x64 output tile, one 4x4 mini per thread
    {
        const int oi0 = (tid >> 4) * 4, oj0 = (tid & 15) * 4;
        float win[6][6];
#pragma unroll
        for (int r = 0; r < 6; ++r) {
            const float* p = &bufT[(oi0 + r) * 72 + oj0];
            float4 a4 = *(const float4*)p;
            float2 b2 = *(const float2*)(p + 4);
            win[r][0] = a4.x; win[r][1] = a4.y; win[r][2] = a4.z; win[r][3] = a4.w;
            win[r][4] = b2.x; win[r][5] = b2.y;
        }
        float* oim = out + (size_t)img * IMG_H * IMG_W;
#pragma unroll
        for (int a = 0; a < 4; ++a) {
            float res[4];
#pragma unroll
            for (int b = 0; b < 4; ++b) {
                float acc = bd0;
#pragma unroll
                for (int dy = 0; dy < 3; ++dy)
#pragma unroll
                    for (int dx = 0; dx < 3; ++dx)
                        acc += wd9[3 * dy + dx] * win[a + dy][b + dx];
                res[b] = frelu(acc) * we0 + be0;
            }
            *(float4*)&oim[(size_t)(r0 + oi0 + a) * IMG_W + c0 + oj0] =
                make_float4(res[0], res[1], res[2], res[3]);
        }
    }
}

// ---------------------------------------------------------------------------
extern "C" void kernel_launch(void* const* d_in, const int* in_sizes, int n_in,
                              void* d_out, int out_size, void* d_ws, size_t ws_size,
                              hipStream_t stream)
{
    const float* x   = (const float*)d_in[0];
    const float* wa  = (const float*)d_in[1];
    const float* ba  = (const float*)d_in[2];
    const float* ga  = (const float*)d_in[3];
    const float* bta = (const float*)d_in[4];
    const float* ma  = (const float*)d_in[5];
    const float* va  = (const float*)d_in[6];
    const float* wb  = (const float*)d_in[7];
    const float* bb  = (const float*)d_in[8];
    const float* gb  = (const float*)d_in[9];
    const float* btb = (const float*)d_in[10];
    const float* mb  = (const float*)d_in[11];
    const float* vb  = (const float*)d_in[12];
    const float* wc  = (const float*)d_in[13];
    const float* bc  = (const float*)d_in[14];
    const float* gcp = (const float*)d_in[15];
    const float* btc = (const float*)d_in[16];
    const float* mc  = (const float*)d_in[17];
    const float* vc  = (const float*)d_in[18];
    const float* wd  = (const float*)d_in[19];
    const float* bd  = (const float*)d_in[20];
    const float* we  = (const float*)d_in[21];
    const float* be  = (const float*)d_in[22];

    float* outp  = (float*)d_out;
    float* x1buf = (float*)d_ws;   // 128 MB: holds x1, then t in place
    float* i1buf = outp;           // d_out doubles as i1 scratch until k_tail

    k_conv_rowscan<<<dim3(NIMG * 128), dim3(256), 0, stream>>>(
        x, wa, ba, ga, bta, ma, va, x1buf, i1buf);
    k_colscan<<<dim3(NIMG * 16), dim3(64), 0, stream>>>(i1buf, x1buf);
    k_tail<<<dim3(NIMG * 256), dim3(256), 0, stream>>>(
        x1buf, x, wa, ba, ga, bta, ma, va, wb, bb, gb, btb, mb, vb,
        wc, bc, gcp, btc, mc, vc, wd, bd, we, be, outp);
}

// Round 2
// 481.040 us; speedup vs baseline: 1.3769x; 1.3769x over previous
//
#include <hip/hip_runtime.h>
#include <math.h>

#define EPS 1e-5f
constexpr int IMG_H = 1024;
constexpr int IMG_W = 1024;
constexpr int NIMG  = 32;

__device__ __forceinline__ float frelu(float v) { return fmaxf(v, 0.f); }

// ===========================================================================
// K1: per-8-row-strip column max of x1 = relu(bn(conv3x3_wa(x))) -> M8.
// Block = 256 = 4 waves; wave wv computes rows rb=strip*8+2wv, rb+1.
// Lane l owns cols {4(l+64q)+k}; horizontal conv neighbors via shfl.
// ===========================================================================
__global__ __launch_bounds__(256) void k_colmax8(
    const float* __restrict__ x,
    const float* __restrict__ wa, const float* __restrict__ ba,
    const float* __restrict__ ga, const float* __restrict__ bta,
    const float* __restrict__ ma, const float* __restrict__ va,
    float* __restrict__ M8)
{
    const int bid   = blockIdx.x;
    const int img   = bid >> 7;
    const int strip = bid & 127;
    const int lane  = threadIdx.x & 63;
    const int wv    = threadIdx.x >> 6;
    const int rb    = strip * 8 + wv * 2;

    const float scale = ga[0] * rsqrtf(va[0] + EPS);
    float w_s[9];
#pragma unroll
    for (int k = 0; k < 9; ++k) w_s[k] = wa[k] * scale;
    const float bias = (ba[0] - ma[0]) * scale + bta[0];

    const float* xim = x + (size_t)img * IMG_H * IMG_W;

    float4 X[4][4];
#pragma unroll
    for (int ri = 0; ri < 4; ++ri) {
        const int gr = rb - 1 + ri;
        if (gr >= 0 && gr < IMG_H) {
            const float4* rp = (const float4*)(xim + (size_t)gr * IMG_W);
#pragma unroll
            for (int q = 0; q < 4; ++q) X[ri][q] = rp[lane + 64 * q];
        } else {
#pragma unroll
            for (int q = 0; q < 4; ++q) X[ri][q] = make_float4(0.f, 0.f, 0.f, 0.f);
        }
    }

    float4 wm[4];
#pragma unroll
    for (int rr = 0; rr < 2; ++rr) {
#pragma unroll
        for (int q = 0; q < 4; ++q) {
            float acc0 = bias, acc1 = bias, acc2 = bias, acc3 = bias;
#pragma unroll
            for (int dy = 0; dy < 3; ++dy) {
                float4 C = X[rr + dy][q];
                float Lw = __shfl_up(C.w, 1, 64);
                float Bq = 0.f;
                if (q > 0) Bq = __shfl(X[rr + dy][q - 1].w, 63, 64);
                if (lane == 0) Lw = Bq;
                float Rx = __shfl_down(C.x, 1, 64);
                float Aq = 0.f;
                if (q < 3) Aq = __shfl(X[rr + dy][q + 1].x, 0, 64);
                if (lane == 63) Rx = Aq;
                const float w0 = w_s[3 * dy], w1 = w_s[3 * dy + 1], w2 = w_s[3 * dy + 2];
                acc0 += w0 * Lw  + w1 * C.x + w2 * C.y;
                acc1 += w0 * C.x + w1 * C.y + w2 * C.z;
                acc2 += w0 * C.y + w1 * C.z + w2 * C.w;
                acc3 += w0 * C.z + w1 * C.w + w2 * Rx;
            }
            float4 v = make_float4(frelu(acc0), frelu(acc1), frelu(acc2), frelu(acc3));
            if (rr == 0) wm[q] = v;
            else {
                wm[q].x = fmaxf(wm[q].x, v.x); wm[q].y = fmaxf(wm[q].y, v.y);
                wm[q].z = fmaxf(wm[q].z, v.z); wm[q].w = fmaxf(wm[q].w, v.w);
            }
        }
    }

    __shared__ float4 wmax[4][256];
#pragma unroll
    for (int q = 0; q < 4; ++q) wmax[wv][64 * q + lane] = wm[q];
    __syncthreads();

    const int tid = threadIdx.x;
    float4 m = wmax[0][tid];
    float4 m1 = wmax[1][tid], m2 = wmax[2][tid], m3 = wmax[3][tid];
    m.x = fmaxf(fmaxf(m.x, m1.x), fmaxf(m2.x, m3.x));
    m.y = fmaxf(fmaxf(m.y, m1.y), fmaxf(m2.y, m3.y));
    m.z = fmaxf(fmaxf(m.z, m1.z), fmaxf(m2.z, m3.z));
    m.w = fmaxf(fmaxf(m.w, m1.w), fmaxf(m2.w, m3.w));
    ((float4*)(M8 + ((size_t)img * 128 + strip) * IMG_W))[tid] = m;
}

// ===========================================================================
// K2: in-place exclusive suffix-max over the 128 strip maxes per (img,col).
// S[s] := max over strips > s  (0.0 seed is exact since x1 >= 0).
// ===========================================================================
__global__ __launch_bounds__(256) void k_suffix(float* __restrict__ M8)
{
    const int gid = blockIdx.x * 256 + threadIdx.x;   // 32768 threads
    const int img = gid >> 10;
    const int col = gid & 1023;
    float* p = M8 + (size_t)img * 128 * IMG_W + col;

    float m = 0.f;
    for (int s0 = 112; s0 >= 0; s0 -= 16) {
        float o[16];
#pragma unroll
        for (int j = 0; j < 16; ++j) o[j] = p[(size_t)(s0 + j) * IMG_W];
#pragma unroll
        for (int j = 15; j >= 0; --j) {
            p[(size_t)(s0 + j) * IMG_W] = m;
            m = fmaxf(m, o[j]);
        }
    }
}

// ===========================================================================
// K3: per 8-row strip, recompute x1 rows, row suffix-scan (i1), column
// running max seeded from S8 (i2), write t = i1 + i2.
// ===========================================================================
__global__ __launch_bounds__(256) void k_build_t(
    const float* __restrict__ x,
    const float* __restrict__ wa, const float* __restrict__ ba,
    const float* __restrict__ ga, const float* __restrict__ bta,
    const float* __restrict__ ma, const float* __restrict__ va,
    const float* __restrict__ S8, float* __restrict__ t)
{
    const int bid   = blockIdx.x;
    const int img   = bid >> 7;
    const int strip = bid & 127;
    const int lane  = threadIdx.x & 63;
    const int wv    = threadIdx.x >> 6;
    const int rb    = strip * 8 + wv * 2;

    // seed loads issued early
    const float4* sp = (const float4*)(S8 + ((size_t)img * 128 + strip) * IMG_W);
    float4 seed[4];
#pragma unroll
    for (int q = 0; q < 4; ++q) seed[q] = sp[lane + 64 * q];

    const float scale = ga[0] * rsqrtf(va[0] + EPS);
    float w_s[9];
#pragma unroll
    for (int k = 0; k < 9; ++k) w_s[k] = wa[k] * scale;
    const float bias = (ba[0] - ma[0]) * scale + bta[0];

    const float* xim = x + (size_t)img * IMG_H * IMG_W;
    float*       tim = t + (size_t)img * IMG_H * IMG_W;

    float4 X[4][4];
#pragma unroll
    for (int ri = 0; ri < 4; ++ri) {
        const int gr = rb - 1 + ri;
        if (gr >= 0 && gr < IMG_H) {
            const float4* rp = (const float4*)(xim + (size_t)gr * IMG_W);
#pragma unroll
            for (int q = 0; q < 4; ++q) X[ri][q] = rp[lane + 64 * q];
        } else {
#pragma unroll
            for (int q = 0; q < 4; ++q) X[ri][q] = make_float4(0.f, 0.f, 0.f, 0.f);
        }
    }

    float4 v[2][4], i1[2][4];
#pragma unroll
    for (int rr = 0; rr < 2; ++rr) {
#pragma unroll
        for (int q = 0; q < 4; ++q) {
            float acc0 = bias, acc1 = bias, acc2 = bias, acc3 = bias;
#pragma unroll
            for (int dy = 0; dy < 3; ++dy) {
                float4 C = X[rr + dy][q];
                float Lw = __shfl_up(C.w, 1, 64);
                float Bq = 0.f;
                if (q > 0) Bq = __shfl(X[rr + dy][q - 1].w, 63, 64);
                if (lane == 0) Lw = Bq;
                float Rx = __shfl_down(C.x, 1, 64);
                float Aq = 0.f;
                if (q < 3) Aq = __shfl(X[rr + dy][q + 1].x, 0, 64);
                if (lane == 63) Rx = Aq;
                const float w0 = w_s[3 * dy], w1 = w_s[3 * dy + 1], w2 = w_s[3 * dy + 2];
                acc0 += w0 * Lw  + w1 * C.x + w2 * C.y;
                acc1 += w0 * C.x + w1 * C.y + w2 * C.z;
                acc2 += w0 * C.y + w1 * C.z + w2 * C.w;
                acc3 += w0 * C.z + w1 * C.w + w2 * Rx;
            }
            v[rr][q] = make_float4(frelu(acc0), frelu(acc1), frelu(acc2), frelu(acc3));
        }
        // reverse (suffix) max scan across the full 1024-wide row
        float4 s[4]; float T[4]; float e[4];
#pragma unroll
        for (int q = 0; q < 4; ++q) {
            float s3 = v[rr][q].w;
            float s2 = fmaxf(v[rr][q].z, s3);
            float s1 = fmaxf(v[rr][q].y, s2);
            float s0 = fmaxf(v[rr][q].x, s1);
            s[q] = make_float4(s0, s1, s2, s3);
            float mm = s0;
#pragma unroll
            for (int off = 1; off < 64; off <<= 1) {
                float o = __shfl_down(mm, off, 64);
                if (lane + off < 64) mm = fmaxf(mm, o);
            }
            T[q] = __shfl(mm, 0, 64);
            float ex = __shfl_down(mm, 1, 64);
            if (lane == 63) ex = -INFINITY;
            e[q] = ex;
        }
        float R[4];
        R[3] = -INFINITY;
        R[2] = T[3];
        R[1] = fmaxf(T[2], R[2]);
        R[0] = fmaxf(T[1], R[1]);
#pragma unroll
        for (int q = 0; q < 4; ++q) {
            const float ee = fmaxf(e[q], R[q]);
            i1[rr][q] = make_float4(fmaxf(s[q].x, ee), fmaxf(s[q].y, ee),
                                    fmaxf(s[q].z, ee), fmaxf(s[q].w, ee));
        }
    }

    // cross-wave column max (waves below this one within the strip)
    __shared__ float4 wmax[4][256];
#pragma unroll
    for (int q = 0; q < 4; ++q) {
        float4 a = v[0][q], b = v[1][q];
        wmax[wv][64 * q + lane] = make_float4(fmaxf(a.x, b.x), fmaxf(a.y, b.y),
                                              fmaxf(a.z, b.z), fmaxf(a.w, b.w));
    }
    __syncthreads();

    float4 acc[4];
#pragma unroll
    for (int q = 0; q < 4; ++q) acc[q] = seed[q];
#pragma unroll
    for (int w2 = 1; w2 < 4; ++w2) {
        if (w2 > wv) {
#pragma unroll
            for (int q = 0; q < 4; ++q) {
                float4 o = wmax[w2][64 * q + lane];
                acc[q].x = fmaxf(acc[q].x, o.x); acc[q].y = fmaxf(acc[q].y, o.y);
                acc[q].z = fmaxf(acc[q].z, o.z); acc[q].w = fmaxf(acc[q].w, o.w);
            }
        }
    }

    float4* o1 = (float4*)(tim + (size_t)(rb)     * IMG_W);
    float4* o2 = (float4*)(tim + (size_t)(rb + 1) * IMG_W);
#pragma unroll
    for (int q = 0; q < 4; ++q) {
        // i2 for lower row (rb+1): includes itself + waves below + seed
        float4 ihi = make_float4(fmaxf(acc[q].x, v[1][q].x), fmaxf(acc[q].y, v[1][q].y),
                                 fmaxf(acc[q].z, v[1][q].z), fmaxf(acc[q].w, v[1][q].w));
        float4 ilo = make_float4(fmaxf(ihi.x, v[0][q].x), fmaxf(ihi.y, v[0][q].y),
                                 fmaxf(ihi.z, v[0][q].z), fmaxf(ihi.w, v[0][q].w));
        o2[lane + 64 * q] = make_float4(i1[1][q].x + ihi.x, i1[1][q].y + ihi.y,
                                        i1[1][q].z + ihi.z, i1[1][q].w + ihi.w);
        o1[lane + 64 * q] = make_float4(i1[0][q].x + ilo.x, i1[0][q].y + ilo.y,
                                        i1[0][q].z + ilo.z, i1[0][q].w + ilo.w);
    }
}

// ===========================================================================
// K4: fused tail.  Per 64x64 output tile:
//   stage t (70x70, 3-halo) -> LDS ; x window preloaded to regs
//   s  = relu(bn(conv_wb(t)) + bn(conv1x1_wc(x)))   (68x68, zero outside img)
//   a1 = relu(bn(conv_wa(s)))                        (66x66, zero outside img)
//   out= conv1x1_we(relu(conv_wd(a1) + bd))          (64x64)
// ===========================================================================
__global__ __launch_bounds__(256) void k_tail(
    const float* __restrict__ t, const float* __restrict__ x,
    const float* __restrict__ wa, const float* __restrict__ ba,
    const float* __restrict__ ga, const float* __restrict__ bta,
    const float* __restrict__ ma, const float* __restrict__ va,
    const float* __restrict__ wb, const float* __restrict__ bb,
    const float* __restrict__ gb, const float* __restrict__ btb,
    const float* __restrict__ mb, const float* __restrict__ vb,
    const float* __restrict__ wc, const float* __restrict__ bc,
    const float* __restrict__ gcp, const float* __restrict__ btc,
    const float* __restrict__ mc, const float* __restrict__ vc,
    const float* __restrict__ wd, const float* __restrict__ bd,
    const float* __restrict__ we, const float* __restrict__ be,
    float* __restrict__ out)
{
    __shared__ float bufT[70 * 72];
    __shared__ float bufS[68 * 72];

    const int bid = blockIdx.x;
    const int img = bid >> 8;
    const int tr  = (bid >> 4) & 15;
    const int tc  = bid & 15;
    const int r0  = tr * 64, c0 = tc * 64;
    const int tid = threadIdx.x;

    const float* tim = t + (size_t)img * IMG_H * IMG_W;
    const float* xim = x + (size_t)img * IMG_H * IMG_W;

    // ---- preload x windows for stage S into registers (hide global latency)
    float xr[2][16];
#pragma unroll
    for (int it = 0; it < 2; ++it) {
        const int mt = tid + 256 * it;
        if (mt < 17 * 17) {
            const int si0 = (mt / 17) * 4, sj0 = (mt % 17) * 4;
#pragma unroll
            for (int a = 0; a < 4; ++a)
#pragma unroll
                for (int b = 0; b < 4; ++b) {
                    const int gr = r0 - 2 + si0 + a, gcc = c0 - 2 + sj0 + b;
                    float xv = 0.f;
                    if ((unsigned)gr < (unsigned)IMG_H && (unsigned)gcc < (unsigned)IMG_W)
                        xv = xim[(size_t)gr * IMG_W + gcc];
                    xr[it][a * 4 + b] = xv;
                }
        }
    }

    // ---- stage t tile (+3 halo), zero padded
    for (int idx = tid; idx < 70 * 70; idx += 256) {
        const int rr = idx / 70, jj = idx - rr * 70;
        const int gr = r0 - 3 + rr, gc2 = c0 - 3 + jj;
        float v = 0.f;
        if ((unsigned)gr < (unsigned)IMG_H && (unsigned)gc2 < (unsigned)IMG_W)
            v = tim[(size_t)gr * IMG_W + gc2];
        bufT[rr * 72 + jj] = v;
    }

    const float sa = ga[0] * rsqrtf(va[0] + EPS);
    float was[9];
#pragma unroll
    for (int k = 0; k < 9; ++k) was[k] = wa[k] * sa;
    const float biasa = (ba[0] - ma[0]) * sa + bta[0];

    const float sb = gb[0] * rsqrtf(vb[0] + EPS);
    float wbs[9];
#pragma unroll
    for (int k = 0; k < 9; ++k) wbs[k] = wb[k] * sb;
    const float biasb = (bb[0] - mb[0]) * sb + btb[0];

    const float sc = gcp[0] * rsqrtf(vc[0] + EPS);
    const float kc = wc[0] * sc;
    const float biasc = (bc[0] - mc[0]) * sc + btc[0];

    float wd9[9];
#pragma unroll
    for (int k = 0; k < 9; ++k) wd9[k] = wd[k];
    const float bd0 = bd[0], we0 = we[0], be0 = be[0];

    __syncthreads();

    // ---- stage S: 68x68 at (r0-2, c0-2)
#pragma unroll
    for (int it = 0; it < 2; ++it) {
        const int mt = tid + 256 * it;
        if (mt < 17 * 17) {
            const int si0 = (mt / 17) * 4, sj0 = (mt % 17) * 4;
            float win[6][6];
#pragma unroll
            for (int r = 0; r < 6; ++r) {
                const float* p = &bufT[(si0 + r) * 72 + sj0];
                float4 a4 = *(const float4*)p;
                float2 b2 = *(const float2*)(p + 4);
                win[r][0] = a4.x; win[r][1] = a4.y; win[r][2] = a4.z; win[r][3] = a4.w;
                win[r][4] = b2.x; win[r][5] = b2.y;
            }
#pragma unroll
            for (int a = 0; a < 4; ++a) {
                float res[4];
#pragma unroll
                for (int b = 0; b < 4; ++b) {
                    float acc = biasb;
#pragma unroll
                    for (int dy = 0; dy < 3; ++dy)
#pragma unroll
                        for (int dx = 0; dx < 3; ++dx)
                            acc += wbs[3 * dy + dx] * win[a + dy][b + dx];
                    const int gr = r0 - 2 + si0 + a, gcc = c0 - 2 + sj0 + b;
                    float sres = 0.f;
                    if ((unsigned)gr < (unsigned)IMG_H && (unsigned)gcc < (unsigned)IMG_W)
                        sres = frelu(acc + xr[it][a * 4 + b] * kc + biasc);
                    res[b] = sres;
                }
                *(float4*)&bufS[(si0 + a) * 72 + sj0] =
                    make_float4(res[0], res[1], res[2], res[3]);
            }
        }
    }
    __syncthreads();

    // ---- stage A: 66x66 at (r0-1, c0-1), written into bufT (t is dead)
#pragma unroll
    for (int it = 0; it < 2; ++it) {
        const int mt = tid + 256 * it;
        if (mt < 17 * 17) {
            const int ai0 = (mt / 17) * 4, aj0 = (mt % 17) * 4;
            float win[6][6];
#pragma unroll
            for (int r = 0; r < 6; ++r) {
                const int rrow = (ai0 + r < 68) ? (ai0 + r) : 67;
                const float* p = &bufS[rrow * 72 + aj0];
                float4 a4 = *(const float4*)p;
                float2 b2 = *(const float2*)(p + 4);
                win[r][0] = a4.x; win[r][1] = a4.y; win[r][2] = a4.z; win[r][3] = a4.w;
                win[r][4] = b2.x; win[r][5] = b2.y;
            }
#pragma unroll
            for (int a = 0; a < 4; ++a) {
                float res[4];
#pragma unroll
                for (int b = 0; b < 4; ++b) {
                    float acc = biasa;
#pragma unroll
                    for (int dy = 0; dy < 3; ++dy)
#pragma unroll
                        for (int dx = 0; dx < 3; ++dx)
                            acc += was[3 * dy + dx] * win[a + dy][b + dx];
                    const int gr = r0 - 1 + ai0 + a, gcc = c0 - 1 + aj0 + b;
                    float r1 = 0.f;
                    if ((unsigned)gr < (unsigned)IMG_H && (unsigned)gcc < (unsigned)IMG_W)
                        r1 = frelu(acc);
                    res[b] = r1;
                }
                *(float4*)&bufT[(ai0 + a) * 72 + aj0] =
                    make_float4(res[0], res[1], res[2], res[3]);
            }
        }
    }
    __syncthreads();

    // ---- final 64x64 tile, one 4x4 mini per thread
    {
        const int oi0 = (tid >> 4) * 4, oj0 = (tid & 15) * 4;
        float win[6][6];
#pragma unroll
        for (int r = 0; r < 6; ++r) {
            const float* p = &bufT[(oi0 + r) * 72 + oj0];
            float4 a4 = *(const float4*)p;
            float2 b2 = *(const float2*)(p + 4);
            win[r][0] = a4.x; win[r][1] = a4.y; win[r][2] = a4.z; win[r][3] = a4.w;
            win[r][4] = b2.x; win[r][5] = b2.y;
        }
        float* oim = out + (size_t)img * IMG_H * IMG_W;
#pragma unroll
        for (int a = 0; a < 4; ++a) {
            float res[4];
#pragma unroll
            for (int b = 0; b < 4; ++b) {
                float acc = bd0;
#pragma unroll
                for (int dy = 0; dy < 3; ++dy)
#pragma unroll
                    for (int dx = 0; dx < 3; ++dx)
                        acc += wd9[3 * dy + dx] * win[a + dy][b + dx];
                res[b] = frelu(acc) * we0 + be0;
            }
            *(float4*)&oim[(size_t)(r0 + oi0 + a) * IMG_W + c0 + oj0] =
                make_float4(res[0], res[1], res[2], res[3]);
        }
    }
}

// ===========================================================================
extern "C" void kernel_launch(void* const* d_in, const int* in_sizes, int n_in,
                              void* d_out, int out_size, void* d_ws, size_t ws_size,
                              hipStream_t stream)
{
    const float* x   = (const float*)d_in[0];
    const float* wa  = (const float*)d_in[1];
    const float* ba  = (const float*)d_in[2];
    const float* ga  = (const float*)d_in[3];
    const float* bta = (const float*)d_in[4];
    const float* ma  = (const float*)d_in[5];
    const float* va  = (const float*)d_in[6];
    const float* wb  = (const float*)d_in[7];
    const float* bb  = (const float*)d_in[8];
    const float* gb  = (const float*)d_in[9];
    const float* btb = (const float*)d_in[10];
    const float* mb  = (const float*)d_in[11];
    const float* vb  = (const float*)d_in[12];
    const float* wc  = (const float*)d_in[13];
    const float* bc  = (const float*)d_in[14];
    const float* gcp = (const float*)d_in[15];
    const float* btc = (const float*)d_in[16];
    const float* mc  = (const float*)d_in[17];
    const float* vc  = (const float*)d_in[18];
    const float* wd  = (const float*)d_in[19];
    const float* bd  = (const float*)d_in[20];
    const float* we  = (const float*)d_in[21];
    const float* be  = (const float*)d_in[22];

    float* outp = (float*)d_out;
    float* tbuf = (float*)d_ws;        // 134 MB: t tensor
    float* M8   = outp;                // d_out holds M8 / suffix table until k_tail

    k_colmax8<<<dim3(NIMG * 128), dim3(256), 0, stream>>>(
        x, wa, ba, ga, bta, ma, va, M8);
    k_suffix<<<dim3(128), dim3(256), 0, stream>>>(M8);
    k_build_t<<<dim3(NIMG * 128), dim3(256), 0, stream>>>(
        x, wa, ba, ga, bta, ma, va, M8, tbuf);
    k_tail<<<dim3(NIMG * 256), dim3(256), 0, stream>>>(
        tbuf, x, wa, ba, ga, bta, ma, va, wb, bb, gb, btb, mb, vb,
        wc, bc, gcp, btc, mc, vc, wd, bd, we, be, outp);
}